// Round 2
// 942.641 us; speedup vs baseline: 1.0247x; 1.0247x over previous
//
#include <hip/hip_runtime.h>

#define NNODES 2000
#define BATCH  64
#define DIM    256
#define GRID   256
#define BLOCK  256

typedef __attribute__((ext_vector_type(8))) short  v8s;
typedef __attribute__((ext_vector_type(8))) __bf16 v8bf;
typedef __attribute__((ext_vector_type(4))) float  v4f;

__device__ __forceinline__ short f2bf(float f) {
  unsigned u = __builtin_bit_cast(unsigned, f);
  u += 0x7FFFu + ((u >> 16) & 1u);            // RNE
  return (short)(u >> 16);
}
__device__ __forceinline__ float bf2f(short s) {
  unsigned u = ((unsigned)(unsigned short)s) << 16;
  return __builtin_bit_cast(float, u);
}
__device__ __forceinline__ v4f mfma16(v8s a, v8s b, v4f c) {
  return __builtin_amdgcn_mfma_f32_16x16x32_bf16(
      __builtin_bit_cast(v8bf, a), __builtin_bit_cast(v8bf, b), c, 0, 0, 0);
}
__device__ __forceinline__ float sigmoidf(float x) {
  return __builtin_amdgcn_rcpf(1.0f + __builtin_amdgcn_exp2f(-1.4426950408889634f * x));
}

// Prep: Wt_in[j][k] = bf16(W_in[k][j]) (256x256);
//       Wt_inner[j][k] = bf16(k<256 ? W_inner[k][j]+W_inner[k+256][j] : W_inner[k+256][j]) (256x512);
//       done[] = 0.
__global__ void prep_kernel(const float* __restrict__ W_in, const float* __restrict__ W_inner,
                            short* __restrict__ Wt_in, short* __restrict__ Wt_inner,
                            int* __restrict__ done) {
  int idx = blockIdx.x * blockDim.x + threadIdx.x;
  int stride = gridDim.x * blockDim.x;
  for (int i = idx; i < 256 * 256; i += stride) {
    int j = i >> 8, k = i & 255;
    Wt_in[j * 256 + k] = f2bf(W_in[k * 256 + j]);
  }
  for (int i = idx; i < 256 * 512; i += stride) {
    int j = i >> 9, k = i & 511;
    float v = W_inner[(k + 256) * 256 + j];
    if (k < 256) v += W_inner[k * 256 + j];
    Wt_inner[j * 512 + k] = f2bf(v);
  }
  for (int i = idx; i < NNODES; i += stride) done[i] = 0;
}

// Dataflow tree evaluation. Children indices > parent index; blocks walk nodes in
// descending order => the highest-index unfinished node is always ready => no deadlock
// (all blocks co-resident via cooperative launch, 1 block/CU).
//
// K-loop is BARRIER-FREE: each wave owns a disjoint 64-column output slice, so its W
// fragments come straight from L2 into registers (double-buffered) -- no cooperative
// LDS staging, no per-kc barrier pair. Barriers per node: ~66 -> ~6.
// Xs is 32 rows x 512 k (32 KiB, NOT 64 KiB: a 64 KiB static block made the
// cooperative launch fail silently last round), XOR-swizzled by row so both the
// v8s pooled-build writes and the ds_read_b128 A-fragment reads are bank-optimal
// (8 accesses/bank for a wave64 b128 op).
__launch_bounds__(BLOCK, 1)
__global__ void tree_kernel(const int* __restrict__ structure, const float* __restrict__ features,
                            const float* __restrict__ b_in, const float* __restrict__ b_inner,
                            const short* __restrict__ Wt_in, const short* __restrict__ Wt_inner,
                            short* __restrict__ state, int* done, float* __restrict__ out) {
  // physical chunk = (k>>3) ^ (row&7), row stride 512 shorts
  __shared__ short Xs[32 * 512];

  const int tid  = threadIdx.x;
  const int wave = tid >> 6;
  const int lane = tid & 63;
  const int ln15 = lane & 15;
  const int quad = lane >> 4;
  const int rl3  = ln15 & 7;

  const int bl  = tid >> 3;           // 0..31: batch row (within half) this thread pools
  const int d0  = (tid & 7) << 5;     // dim block [d0, d0+32)
  const int swb = bl & 7;

  // j = wave*64 + nt*16 + ln15 is node-invariant: hoist bias loads out of the loop
  float bia_in[4], bia_nn[4];
  #pragma unroll
  for (int nt = 0; nt < 4; ++nt) {
    const int j = wave * 64 + nt * 16 + ln15;
    bia_in[nt] = b_in[j];
    bia_nn[nt] = b_inner[j];
  }

  for (int node = NNODES - 1 - (int)blockIdx.x; node >= 0; node -= GRID) {
    const int s = structure[2 * node];
    const int e = structure[2 * node + 1];
    const bool leaf = (s < 0);
    const int K = leaf ? 256 : 512;
    const short* __restrict__ W = leaf ? Wt_in : Wt_inner;

    if (!leaf) {
      // parallel child poll: lane i of wave 0 spins on child s+i (nc <= 4)
      if (wave == 0 && lane < e - s) {
        int g = 0;
        while (atomicAdd(&done[s + lane], 0) == 0 && g < (1 << 22)) {
          __builtin_amdgcn_s_sleep(2); ++g;
        }
      }
      __syncthreads();
      __threadfence();   // acquire: see producer's state stores (cross-XCD)
    }

    for (int half = 0; half < 2; ++half) {
      __syncthreads();   // WAR: prior GEMM's Xs reads are complete

      // ---- build Xs (bf16) for batch rows [half*32, half*32+32) ----
      const int b = half * 32 + bl;
      const float* __restrict__ fp = features + ((size_t)b * NNODES + node) * DIM + d0;
      if (leaf) {
        #pragma unroll
        for (int d = 0; d < 32; d += 8) {
          const float4 f0 = *(const float4*)(fp + d);
          const float4 f1 = *(const float4*)(fp + d + 4);
          v8s o;
          o[0] = f2bf(f0.x); o[1] = f2bf(f0.y); o[2] = f2bf(f0.z); o[3] = f2bf(f0.w);
          o[4] = f2bf(f1.x); o[5] = f2bf(f1.y); o[6] = f2bf(f1.z); o[7] = f2bf(f1.w);
          const int ch = (d0 + d) >> 3;
          *(v8s*)&Xs[(bl << 9) + ((ch ^ swb) << 3)] = o;
        }
      } else {
        const float inv = 1.0f / (float)(e - s + 1);
        #pragma unroll
        for (int d = 0; d < 32; d += 8) {
          const float4 f0 = *(const float4*)(fp + d);
          const float4 f1 = *(const float4*)(fp + d + 4);
          float sm[8] = {f0.x, f0.y, f0.z, f0.w, f1.x, f1.y, f1.z, f1.w};
          float mn[8];
          #pragma unroll
          for (int q = 0; q < 8; ++q) mn[q] = sm[q];
          for (int c = s; c < e; ++c) {
            const v8s cv = *(const v8s*)(state + ((size_t)c * BATCH + b) * DIM + d0 + d);
            #pragma unroll
            for (int q = 0; q < 8; ++q) {
              const float v = bf2f(cv[q]);
              sm[q] += v; mn[q] = fminf(mn[q], v);
            }
          }
          v8s om, on;
          #pragma unroll
          for (int q = 0; q < 8; ++q) { om[q] = f2bf(sm[q] * inv); on[q] = f2bf(mn[q]); }
          const int ch = (d0 + d) >> 3;
          *(v8s*)&Xs[(bl << 9) + ((ch ^ swb) << 3)]        = om;  // c_mean: k in [0,256)
          *(v8s*)&Xs[(bl << 9) + (((ch + 32) ^ swb) << 3)] = on;  // c_min:  k in [256,512)
        }
      }
      __syncthreads();   // Xs ready

      // ---- GEMM: [32 x K] @ Wt^T -> [32 x 256]; W fragments straight from L2 ----
      v4f acc[2][4];
      #pragma unroll
      for (int mt = 0; mt < 2; ++mt)
        #pragma unroll
        for (int nt = 0; nt < 4; ++nt) acc[mt][nt] = v4f{0.f, 0.f, 0.f, 0.f};

      const short* __restrict__ Wp = W + (wave * 64 + ln15) * K + quad * 8;
      const int nkc = K >> 5;
      v8s bcur[4];
      #pragma unroll
      for (int nt = 0; nt < 4; ++nt) bcur[nt] = *(const v8s*)(Wp + nt * 16 * K);
      for (int kc = 0; kc < nkc; ++kc) {
        const int kn = (kc + 1 < nkc) ? kc + 1 : kc;   // last iter: harmless re-load
        v8s bnxt[4];
        #pragma unroll
        for (int nt = 0; nt < 4; ++nt) bnxt[nt] = *(const v8s*)(Wp + nt * 16 * K + kn * 32);
        v8s af[2];
        #pragma unroll
        for (int mt = 0; mt < 2; ++mt) {
          const int r = mt * 16 + ln15;               // r&7 == rl3
          af[mt] = *(const v8s*)&Xs[(r << 9) + (((kc * 4 + quad) ^ rl3) << 3)];
        }
        #pragma unroll
        for (int mt = 0; mt < 2; ++mt)
          #pragma unroll
          for (int nt = 0; nt < 4; ++nt)
            acc[mt][nt] = mfma16(af[mt], bcur[nt], acc[mt][nt]);
        #pragma unroll
        for (int nt = 0; nt < 4; ++nt) bcur[nt] = bnxt[nt];
      }

      // ---- epilogue: bias + sigmoid, store state (bf16) and root output (fp32) ----
      #pragma unroll
      for (int mt = 0; mt < 2; ++mt) {
        #pragma unroll
        for (int nt = 0; nt < 4; ++nt) {
          const int j = wave * 64 + nt * 16 + ln15;
          const float bs = leaf ? bia_in[nt] : bia_nn[nt];
          #pragma unroll
          for (int r = 0; r < 4; ++r) {
            const int bb = half * 32 + mt * 16 + quad * 4 + r;
            const float v = sigmoidf(acc[mt][nt][r] + bs);
            state[((size_t)node * BATCH + bb) * DIM + j] = f2bf(v);
            if (node == 0) out[bb * DIM + j] = v;
          }
        }
      }
    } // half

    __threadfence();      // release: make state stores device-visible
    __syncthreads();      // all threads' stores fenced before flag
    if (tid == 0) atomicExch(&done[node], 1);
  }
}

extern "C" void kernel_launch(void* const* d_in, const int* in_sizes, int n_in,
                              void* d_out, int out_size, void* d_ws, size_t ws_size,
                              hipStream_t stream) {
  const int*   structure = (const int*)d_in[0];
  const float* features  = (const float*)d_in[1];
  const float* W_in      = (const float*)d_in[2];
  const float* b_in      = (const float*)d_in[3];
  const float* W_inner   = (const float*)d_in[4];
  const float* b_inner   = (const float*)d_in[5];
  float* out = (float*)d_out;

  char* ws = (char*)d_ws;
  short* state = (short*)ws;                                   // 2000*64*256*2 = 65,536,000 B
  size_t off = (size_t)NNODES * BATCH * DIM * 2;
  short* Wt_in = (short*)(ws + off);    off += 256 * 256 * 2;  // 131,072 B
  short* Wt_inner = (short*)(ws + off); off += 512 * 256 * 2;  // 262,144 B
  int* done = (int*)(ws + off);                                 // 8,000 B

  prep_kernel<<<dim3(256), dim3(256), 0, stream>>>(W_in, W_inner, Wt_in, Wt_inner, done);

  void* args[9];
  args[0] = (void*)&structure;
  args[1] = (void*)&features;
  args[2] = (void*)&b_in;
  args[3] = (void*)&b_inner;
  args[4] = (void*)&Wt_in;
  args[5] = (void*)&Wt_inner;
  args[6] = (void*)&state;
  args[7] = (void*)&done;
  args[8] = (void*)&out;
  hipLaunchCooperativeKernel((void*)tree_kernel, dim3(GRID), dim3(BLOCK), args, 0, stream);
}

// Round 3
// 833.573 us; speedup vs baseline: 1.1588x; 1.1308x over previous
//
#include <hip/hip_runtime.h>
#include <hip/hip_cooperative_groups.h>

namespace cg = cooperative_groups;

#define NNODES 2000
#define BATCH  64
#define DIM    256
#define GRID   256
#define BLOCK  256
#define MAXLVL 128

typedef __attribute__((ext_vector_type(8))) short  v8s;
typedef __attribute__((ext_vector_type(8))) __bf16 v8bf;
typedef __attribute__((ext_vector_type(4))) float  v4f;

__device__ __forceinline__ short f2bf(float f) {
  unsigned u = __builtin_bit_cast(unsigned, f);
  u += 0x7FFFu + ((u >> 16) & 1u);            // RNE
  return (short)(u >> 16);
}
__device__ __forceinline__ float bf2f(short s) {
  unsigned u = ((unsigned)(unsigned short)s) << 16;
  return __builtin_bit_cast(float, u);
}
__device__ __forceinline__ v4f mfma16(v8s a, v8s b, v4f c) {
  return __builtin_amdgcn_mfma_f32_16x16x32_bf16(
      __builtin_bit_cast(v8bf, a), __builtin_bit_cast(v8bf, b), c, 0, 0, 0);
}
__device__ __forceinline__ float sigmoidf(float x) {
  return __builtin_amdgcn_rcpf(1.0f + __builtin_amdgcn_exp2f(-1.4426950408889634f * x));
}

// Prep: Wt_in[j][k] = bf16(W_in[k][j]) (256x256);
//       Wt_inner[j][k] = bf16(k<256 ? W_inner[k][j]+W_inner[k+256][j] : W_inner[k+256][j]) (256x512).
__global__ void prep_kernel(const float* __restrict__ W_in, const float* __restrict__ W_inner,
                            short* __restrict__ Wt_in, short* __restrict__ Wt_inner) {
  int idx = blockIdx.x * blockDim.x + threadIdx.x;
  int stride = gridDim.x * blockDim.x;
  for (int i = idx; i < 256 * 256; i += stride) {
    int j = i >> 8, k = i & 255;
    Wt_in[j * 256 + k] = f2bf(W_in[k * 256 + j]);
  }
  for (int i = idx; i < 256 * 512; i += stride) {
    int j = i >> 9, k = i & 511;
    float v = W_inner[(k + 256) * 256 + j];
    if (k < 256) v += W_inner[k * 256 + j];
    Wt_inner[j * 512 + k] = f2bf(v);
  }
}

// Level-synchronous tree evaluation.
// Phase A (block-local, redundant per block, deterministic => identical everywhere):
//   stage structure in LDS, compute node heights to fixpoint, bucket nodes by height.
// Phase B: for each level (leaves = height 0 first): process that level's nodes
//   strided across blocks, then ONE grid.sync(). This replaces the per-node
//   done-flag dataflow whose per-node __threadfence (whole-L2 writeback/invalidate)
//   dominated the critical path (R2: 787us at 1.2% MfmaUtil despite barrier-free GEMM).
// Fence cost is now paid ~12x per dispatch (concurrently across XCDs) instead of ~4096x.
__launch_bounds__(BLOCK, 1)
__global__ void tree_kernel(const int* __restrict__ structure, const float* __restrict__ features,
                            const float* __restrict__ b_in, const float* __restrict__ b_inner,
                            const short* __restrict__ Wt_in, const short* __restrict__ Wt_inner,
                            short* __restrict__ state, float* __restrict__ out) {
  // Xs: 32 batch rows x 512 k (bf16), XOR-swizzled chunks: phys chunk = (k>>3) ^ (row&7).
  __shared__ short Xs[32 * 512];        // 32 KiB
  __shared__ int   structS[NNODES * 2]; // 16 KiB
  __shared__ short order[NNODES];       // 4 KiB: node ids sorted by (height, index)
  __shared__ short h[NNODES];           // 4 KiB: node heights
  __shared__ int   lstart[MAXLVL + 1];
  __shared__ int   counts[MAXLVL];
  __shared__ int   chg, Hlev;

  const int tid  = threadIdx.x;
  const int wave = tid >> 6;
  const int lane = tid & 63;
  const int ln15 = lane & 15;
  const int quad = lane >> 4;
  const int rl3  = ln15 & 7;

  const int bl  = tid >> 3;           // 0..31: batch row (within half) this thread pools
  const int d0  = (tid & 7) << 5;     // dim block [d0, d0+32)
  const int swb = bl & 7;

  // ---- Phase A: structure -> LDS, heights, level buckets ----
  for (int i = tid; i < NNODES * 2; i += BLOCK) structS[i] = structure[i];
  for (int i = tid; i < NNODES; i += BLOCK) h[i] = 0;
  for (int i = tid; i < MAXLVL; i += BLOCK) counts[i] = 0;
  __syncthreads();

  for (int pass = 0; pass < 4096; ++pass) {
    if (tid == 0) chg = 0;
    __syncthreads();
    int any = 0;
    for (int i = tid; i < NNODES; i += BLOCK) {
      const int s = structS[2 * i];
      if (s >= 0) {
        const int e = structS[2 * i + 1];
        int m = 0;
        for (int c = s; c < e; ++c) m = max(m, (int)h[c]);
        if (m + 1 > (int)h[i]) { h[i] = (short)(m + 1); any = 1; }
      }
    }
    if (any) chg = 1;
    __syncthreads();
    if (chg == 0) break;
    __syncthreads();
  }

  for (int i = tid; i < NNODES; i += BLOCK) atomicAdd(&counts[h[i]], 1);
  __syncthreads();
  if (tid == 0) {
    int acc = 0, hm = 0;
    for (int l = 0; l < MAXLVL; ++l) {
      lstart[l] = acc; acc += counts[l];
      if (counts[l] > 0) hm = l + 1;
    }
    lstart[MAXLVL] = acc;
    Hlev = hm;
  }
  __syncthreads();
  // deterministic stable scatter: wave w handles levels w, w+4, ...
  for (int lev = wave; lev < Hlev; lev += 4) {
    int cnt = lstart[lev];
    for (int base = 0; base < NNODES; base += 64) {
      const int i = base + lane;
      const bool p = (i < NNODES) && ((int)h[i] == lev);
      const unsigned long long m = __ballot(p);
      if (p) order[cnt + (int)__popcll(m & ((1ull << lane) - 1ull))] = (short)i;
      cnt += (int)__popcll(m);
    }
  }

  // j = wave*64 + nt*16 + ln15 is node-invariant: hoist bias loads
  float bia_in[4], bia_nn[4];
  #pragma unroll
  for (int nt = 0; nt < 4; ++nt) {
    const int j = wave * 64 + nt * 16 + ln15;
    bia_in[nt] = b_in[j];
    bia_nn[nt] = b_inner[j];
  }
  __syncthreads();

  cg::grid_group grid = cg::this_grid();
  const int H = Hlev;

  // ---- Phase B: level-synchronous sweep, leaves first ----
  for (int lev = 0; lev < H; ++lev) {
    const int kbeg = lstart[lev], kend = lstart[lev + 1];
    for (int k = kbeg + (int)blockIdx.x; k < kend; k += GRID) {
      const int node = order[k];
      const int s = structS[2 * node];
      const int e = structS[2 * node + 1];
      const bool leaf = (s < 0);
      const int K = leaf ? 256 : 512;
      const short* __restrict__ W = leaf ? Wt_in : Wt_inner;

      for (int half = 0; half < 2; ++half) {
        __syncthreads();   // WAR: prior GEMM's Xs reads are complete

        // ---- build Xs (bf16) for batch rows [half*32, half*32+32) ----
        const int b = half * 32 + bl;
        const float* __restrict__ fp = features + ((size_t)b * NNODES + node) * DIM + d0;
        if (leaf) {
          #pragma unroll
          for (int d = 0; d < 32; d += 8) {
            const float4 f0 = *(const float4*)(fp + d);
            const float4 f1 = *(const float4*)(fp + d + 4);
            v8s o;
            o[0] = f2bf(f0.x); o[1] = f2bf(f0.y); o[2] = f2bf(f0.z); o[3] = f2bf(f0.w);
            o[4] = f2bf(f1.x); o[5] = f2bf(f1.y); o[6] = f2bf(f1.z); o[7] = f2bf(f1.w);
            const int ch = (d0 + d) >> 3;
            *(v8s*)&Xs[(bl << 9) + ((ch ^ swb) << 3)] = o;
          }
        } else {
          const float inv = 1.0f / (float)(e - s + 1);
          #pragma unroll
          for (int d = 0; d < 32; d += 8) {
            const float4 f0 = *(const float4*)(fp + d);
            const float4 f1 = *(const float4*)(fp + d + 4);
            float sm[8] = {f0.x, f0.y, f0.z, f0.w, f1.x, f1.y, f1.z, f1.w};
            float mn[8];
            #pragma unroll
            for (int q = 0; q < 8; ++q) mn[q] = sm[q];
            for (int c = s; c < e; ++c) {
              const v8s cv = *(const v8s*)(state + ((size_t)c * BATCH + b) * DIM + d0 + d);
              #pragma unroll
              for (int q = 0; q < 8; ++q) {
                const float v = bf2f(cv[q]);
                sm[q] += v; mn[q] = fminf(mn[q], v);
              }
            }
            v8s om, on;
            #pragma unroll
            for (int q = 0; q < 8; ++q) { om[q] = f2bf(sm[q] * inv); on[q] = f2bf(mn[q]); }
            const int ch = (d0 + d) >> 3;
            *(v8s*)&Xs[(bl << 9) + ((ch ^ swb) << 3)]        = om;  // c_mean: k in [0,256)
            *(v8s*)&Xs[(bl << 9) + (((ch + 32) ^ swb) << 3)] = on;  // c_min:  k in [256,512)
          }
        }
        __syncthreads();   // Xs ready

        // ---- GEMM: [32 x K] @ Wt^T -> [32 x 256]; W fragments straight from L2 ----
        v4f acc[2][4];
        #pragma unroll
        for (int mt = 0; mt < 2; ++mt)
          #pragma unroll
          for (int nt = 0; nt < 4; ++nt) acc[mt][nt] = v4f{0.f, 0.f, 0.f, 0.f};

        const short* __restrict__ Wp = W + (wave * 64 + ln15) * K + quad * 8;
        const int nkc = K >> 5;
        v8s bcur[4];
        #pragma unroll
        for (int nt = 0; nt < 4; ++nt) bcur[nt] = *(const v8s*)(Wp + nt * 16 * K);
        for (int kc = 0; kc < nkc; ++kc) {
          const int kn = (kc + 1 < nkc) ? kc + 1 : kc;   // last iter: harmless re-load
          v8s bnxt[4];
          #pragma unroll
          for (int nt = 0; nt < 4; ++nt) bnxt[nt] = *(const v8s*)(Wp + nt * 16 * K + kn * 32);
          v8s af[2];
          #pragma unroll
          for (int mt = 0; mt < 2; ++mt) {
            const int r = mt * 16 + ln15;               // r&7 == rl3
            af[mt] = *(const v8s*)&Xs[(r << 9) + (((kc * 4 + quad) ^ rl3) << 3)];
          }
          #pragma unroll
          for (int mt = 0; mt < 2; ++mt)
            #pragma unroll
            for (int nt = 0; nt < 4; ++nt)
              acc[mt][nt] = mfma16(af[mt], bcur[nt], acc[mt][nt]);
          #pragma unroll
          for (int nt = 0; nt < 4; ++nt) bcur[nt] = bnxt[nt];
        }

        // ---- epilogue: bias + sigmoid, store state (bf16) and root output (fp32) ----
        #pragma unroll
        for (int mt = 0; mt < 2; ++mt) {
          #pragma unroll
          for (int nt = 0; nt < 4; ++nt) {
            const int j = wave * 64 + nt * 16 + ln15;
            const float bs = leaf ? bia_in[nt] : bia_nn[nt];
            #pragma unroll
            for (int r = 0; r < 4; ++r) {
              const int bb = half * 32 + mt * 16 + quad * 4 + r;
              const float v = sigmoidf(acc[mt][nt][r] + bs);
              state[((size_t)node * BATCH + bb) * DIM + j] = f2bf(v);
              if (node == 0) out[bb * DIM + j] = v;
            }
          }
        }
      } // half
    } // nodes of level

    grid.sync();   // level boundary: one fence for everyone, flushes run concurrently
  }
}

extern "C" void kernel_launch(void* const* d_in, const int* in_sizes, int n_in,
                              void* d_out, int out_size, void* d_ws, size_t ws_size,
                              hipStream_t stream) {
  const int*   structure = (const int*)d_in[0];
  const float* features  = (const float*)d_in[1];
  const float* W_in      = (const float*)d_in[2];
  const float* b_in      = (const float*)d_in[3];
  const float* W_inner   = (const float*)d_in[4];
  const float* b_inner   = (const float*)d_in[5];
  float* out = (float*)d_out;

  char* ws = (char*)d_ws;
  short* state = (short*)ws;                                   // 2000*64*256*2 = 65,536,000 B
  size_t off = (size_t)NNODES * BATCH * DIM * 2;
  short* Wt_in = (short*)(ws + off);    off += 256 * 256 * 2;  // 131,072 B
  short* Wt_inner = (short*)(ws + off); off += 512 * 256 * 2;  // 262,144 B

  prep_kernel<<<dim3(256), dim3(256), 0, stream>>>(W_in, W_inner, Wt_in, Wt_inner);

  void* args[8];
  args[0] = (void*)&structure;
  args[1] = (void*)&features;
  args[2] = (void*)&b_in;
  args[3] = (void*)&b_inner;
  args[4] = (void*)&Wt_in;
  args[5] = (void*)&Wt_inner;
  args[6] = (void*)&state;
  args[7] = (void*)&out;
  hipLaunchCooperativeKernel((void*)tree_kernel, dim3(GRID), dim3(BLOCK), args, 0, stream);
}

// Round 4
// 454.002 us; speedup vs baseline: 2.1276x; 1.8361x over previous
//
#include <hip/hip_runtime.h>

#define NNODES 2000
#define BATCH  64
#define DIM    256
#define GRID   256
#define BLOCK  256

typedef __attribute__((ext_vector_type(8))) short  v8s;
typedef __attribute__((ext_vector_type(8))) __bf16 v8bf;
typedef __attribute__((ext_vector_type(4))) float  v4f;
typedef __attribute__((ext_vector_type(4))) int    v4i;

__device__ __forceinline__ short f2bf(float f) {
  unsigned u = __builtin_bit_cast(unsigned, f);
  u += 0x7FFFu + ((u >> 16) & 1u);            // RNE
  return (short)(u >> 16);
}
__device__ __forceinline__ float bf2f(short s) {
  unsigned u = ((unsigned)(unsigned short)s) << 16;
  return __builtin_bit_cast(float, u);
}
__device__ __forceinline__ v4f mfma16(v8s a, v8s b, v4f c) {
  return __builtin_amdgcn_mfma_f32_16x16x32_bf16(
      __builtin_bit_cast(v8bf, a), __builtin_bit_cast(v8bf, b), c, 0, 0, 0);
}
__device__ __forceinline__ float sigmoidf(float x) {
  return __builtin_amdgcn_rcpf(1.0f + __builtin_amdgcn_exp2f(-1.4426950408889634f * x));
}

// Prep: Wt_in[j][k] = bf16(W_in[k][j]) (256x256);
//       Wt_inner[j][k] = bf16(k<256 ? W_inner[k][j]+W_inner[k+256][j] : W_inner[k+256][j]) (256x512);
//       done[] = 0 (written coherent-at-IF so tree_kernel's bypassing loads see it).
__global__ void prep_kernel(const float* __restrict__ W_in, const float* __restrict__ W_inner,
                            short* __restrict__ Wt_in, short* __restrict__ Wt_inner,
                            int* __restrict__ done) {
  int idx = blockIdx.x * blockDim.x + threadIdx.x;
  int stride = gridDim.x * blockDim.x;
  for (int i = idx; i < 256 * 256; i += stride) {
    int j = i >> 8, k = i & 255;
    Wt_in[j * 256 + k] = f2bf(W_in[k * 256 + j]);
  }
  for (int i = idx; i < 256 * 512; i += stride) {
    int j = i >> 9, k = i & 511;
    float v = W_inner[(k + 256) * 256 + j];
    if (k < 256) v += W_inner[k * 256 + j];
    Wt_inner[j * 512 + k] = f2bf(v);
  }
  for (int i = idx; i < 2 * NNODES; i += stride)
    __hip_atomic_store(&done[i], 0, __ATOMIC_RELAXED, __HIP_MEMORY_SCOPE_AGENT);
}

// Dataflow tree evaluation, ZERO cache-flush fences.
// Cross-block data (state, done flags) moves exclusively through sc0sc1 (bypass
// L1+L2, coherent at Infinity Cache) loads/stores, so per-XCD L2 incoherence is
// irrelevant and W/features stay L2-warm for the entire dispatch. R2/R3 showed
// device-scope threadfence/grid.sync (whole-L2 writeback+invalidate) cost ~40us
// per critical-path link by re-chilling the weight tables.
// Per-half done flags: batch halves are end-to-end independent chains, so a
// parent's half-0 overlaps its child's half-1 (pipelined critical path).
// Deadlock-free: children idx > parent idx, blocks walk nodes descending, all
// blocks co-resident (cooperative launch).
__launch_bounds__(BLOCK, 1)
__global__ void tree_kernel(const int* __restrict__ structure, const float* __restrict__ features,
                            const float* __restrict__ b_in, const float* __restrict__ b_inner,
                            const short* __restrict__ Wt_in, const short* __restrict__ Wt_inner,
                            short* __restrict__ state, int* done, float* __restrict__ out) {
  // 32 batch rows x 512 k (bf16), XOR-swizzled chunks: phys chunk = (k>>3) ^ (row&7).
  __shared__ short Xs[32 * 512];

  const int tid  = threadIdx.x;
  const int wave = tid >> 6;
  const int lane = tid & 63;
  const int ln15 = lane & 15;
  const int quad = lane >> 4;
  const int rl3  = ln15 & 7;

  const int bl  = tid >> 3;           // 0..31: batch row (within half) this thread pools
  const int d0  = (tid & 7) << 5;     // dim block [d0, d0+32)
  const int swb = bl & 7;

  // j = wave*64 + nt*16 + ln15 is node-invariant: hoist bias loads out of the loop
  float bia_in[4], bia_nn[4];
  #pragma unroll
  for (int nt = 0; nt < 4; ++nt) {
    const int j = wave * 64 + nt * 16 + ln15;
    bia_in[nt] = b_in[j];
    bia_nn[nt] = b_inner[j];
  }

  for (int node = NNODES - 1 - (int)blockIdx.x; node >= 0; node -= GRID) {
    const int s = structure[2 * node];
    const int e = structure[2 * node + 1];
    const bool leaf = (s < 0);
    const int nc = e - s;               // 1..4 when inner
    const int K = leaf ? 256 : 512;
    const short* __restrict__ W = leaf ? Wt_in : Wt_inner;

    for (int half = 0; half < 2; ++half) {
      if (!leaf && wave == 0 && lane < nc) {
        // relaxed agent-scope poll (reads IF, no cache invalidation)
        int g = 0;
        while (__hip_atomic_load(&done[2 * (s + lane) + half],
                                 __ATOMIC_RELAXED, __HIP_MEMORY_SCOPE_AGENT) == 0 &&
               g < (1 << 22)) {
          __builtin_amdgcn_s_sleep(1); ++g;
        }
      }
      __syncthreads();   // children's half ready; also WAR on Xs from prior half

      // ---- build Xs (bf16) for batch rows [half*32, half*32+32) ----
      const int b = half * 32 + bl;
      const float* __restrict__ fp = features + ((size_t)b * NNODES + node) * DIM + d0;
      if (leaf) {
        #pragma unroll
        for (int d = 0; d < 32; d += 8) {
          const float4 f0 = *(const float4*)(fp + d);
          const float4 f1 = *(const float4*)(fp + d + 4);
          v8s o;
          o[0] = f2bf(f0.x); o[1] = f2bf(f0.y); o[2] = f2bf(f0.z); o[3] = f2bf(f0.w);
          o[4] = f2bf(f1.x); o[5] = f2bf(f1.y); o[6] = f2bf(f1.z); o[7] = f2bf(f1.w);
          const int ch = (d0 + d) >> 3;
          *(v8s*)&Xs[(bl << 9) + ((ch ^ swb) << 3)] = o;
        }
      } else {
        // issue ALL child loads (sc0 sc1: bypass stale L1/L2, read coherent from IF),
        // then one waitcnt -- IF latency paid once, not per chunk.
        v4i cb[4][4];
        #pragma unroll
        for (int ci = 0; ci < 4; ++ci) {
          if (ci < nc) {   // block-uniform branch
            const short* cp = state + ((size_t)(s + ci) * BATCH + b) * DIM + d0;
            #pragma unroll
            for (int dq = 0; dq < 4; ++dq)
              asm volatile("global_load_dwordx4 %0, %1, off sc0 sc1"
                           : "=v"(cb[ci][dq]) : "v"(cp + dq * 8));
          }
        }
        asm volatile("s_waitcnt vmcnt(0)" ::: "memory");
        __builtin_amdgcn_sched_barrier(0);   // rule #18: pin VALU uses after the wait

        const float inv = 1.0f / (float)(nc + 1);
        #pragma unroll
        for (int dq = 0; dq < 4; ++dq) {
          const float4 f0 = *(const float4*)(fp + dq * 8);
          const float4 f1 = *(const float4*)(fp + dq * 8 + 4);
          float sm[8] = {f0.x, f0.y, f0.z, f0.w, f1.x, f1.y, f1.z, f1.w};
          float mn[8];
          #pragma unroll
          for (int q = 0; q < 8; ++q) mn[q] = sm[q];
          #pragma unroll
          for (int ci = 0; ci < 4; ++ci) {
            if (ci < nc) {
              const v8s cv = __builtin_bit_cast(v8s, cb[ci][dq]);
              #pragma unroll
              for (int q = 0; q < 8; ++q) {
                const float v = bf2f(cv[q]);
                sm[q] += v; mn[q] = fminf(mn[q], v);
              }
            }
          }
          v8s om, on;
          #pragma unroll
          for (int q = 0; q < 8; ++q) { om[q] = f2bf(sm[q] * inv); on[q] = f2bf(mn[q]); }
          const int ch = (d0 + dq * 8) >> 3;
          *(v8s*)&Xs[(bl << 9) + ((ch ^ swb) << 3)]        = om;  // c_mean: k in [0,256)
          *(v8s*)&Xs[(bl << 9) + (((ch + 32) ^ swb) << 3)] = on;  // c_min:  k in [256,512)
        }
      }
      __syncthreads();   // Xs ready

      // ---- GEMM: [32 x K] @ Wt^T -> [32 x 256]; W fragments straight from L2 ----
      v4f acc[2][4];
      #pragma unroll
      for (int mt = 0; mt < 2; ++mt)
        #pragma unroll
        for (int nt = 0; nt < 4; ++nt) acc[mt][nt] = v4f{0.f, 0.f, 0.f, 0.f};

      const short* __restrict__ Wp = W + (wave * 64 + ln15) * K + quad * 8;
      const int nkc = K >> 5;
      v8s bcur[4];
      #pragma unroll
      for (int nt = 0; nt < 4; ++nt) bcur[nt] = *(const v8s*)(Wp + nt * 16 * K);
      for (int kc = 0; kc < nkc; ++kc) {
        const int kn = (kc + 1 < nkc) ? kc + 1 : kc;   // last iter: harmless re-load
        v8s bnxt[4];
        #pragma unroll
        for (int nt = 0; nt < 4; ++nt) bnxt[nt] = *(const v8s*)(Wp + nt * 16 * K + kn * 32);
        v8s af[2];
        #pragma unroll
        for (int mt = 0; mt < 2; ++mt) {
          const int r = mt * 16 + ln15;               // r&7 == rl3
          af[mt] = *(const v8s*)&Xs[(r << 9) + (((kc * 4 + quad) ^ rl3) << 3)];
        }
        #pragma unroll
        for (int mt = 0; mt < 2; ++mt)
          #pragma unroll
          for (int nt = 0; nt < 4; ++nt)
            acc[mt][nt] = mfma16(af[mt], bcur[nt], acc[mt][nt]);
        #pragma unroll
        for (int nt = 0; nt < 4; ++nt) bcur[nt] = bnxt[nt];
      }

      // ---- epilogue: bias + sigmoid; state stored via sc0sc1 (coherent at IF) ----
      #pragma unroll
      for (int mt = 0; mt < 2; ++mt) {
        #pragma unroll
        for (int nt = 0; nt < 4; ++nt) {
          const int j = wave * 64 + nt * 16 + ln15;
          const float bs = leaf ? bia_in[nt] : bia_nn[nt];
          #pragma unroll
          for (int r = 0; r < 4; ++r) {
            const int bb = half * 32 + mt * 16 + quad * 4 + r;
            const float v = sigmoidf(acc[mt][nt][r] + bs);
            short* sp = state + ((size_t)node * BATCH + bb) * DIM + j;
            const int hv = (int)(unsigned short)f2bf(v);
            asm volatile("global_store_short %0, %1, off sc0 sc1" :: "v"(sp), "v"(hv));
            if (node == 0) out[bb * DIM + j] = v;
          }
        }
      }

      asm volatile("s_waitcnt vmcnt(0)" ::: "memory");  // this thread's stores are at IF
      __syncthreads();                                  // => ALL threads' stores are at IF
      if (tid == 0)
        __hip_atomic_store(&done[2 * node + half], 1,
                           __ATOMIC_RELAXED, __HIP_MEMORY_SCOPE_AGENT);
    } // half
  }
}

extern "C" void kernel_launch(void* const* d_in, const int* in_sizes, int n_in,
                              void* d_out, int out_size, void* d_ws, size_t ws_size,
                              hipStream_t stream) {
  const int*   structure = (const int*)d_in[0];
  const float* features  = (const float*)d_in[1];
  const float* W_in      = (const float*)d_in[2];
  const float* b_in      = (const float*)d_in[3];
  const float* W_inner   = (const float*)d_in[4];
  const float* b_inner   = (const float*)d_in[5];
  float* out = (float*)d_out;

  char* ws = (char*)d_ws;
  short* state = (short*)ws;                                   // 2000*64*256*2 = 65,536,000 B
  size_t off = (size_t)NNODES * BATCH * DIM * 2;
  short* Wt_in = (short*)(ws + off);    off += 256 * 256 * 2;  // 131,072 B
  short* Wt_inner = (short*)(ws + off); off += 512 * 256 * 2;  // 262,144 B
  int* done = (int*)(ws + off);                                 // 2*2000*4 = 16,000 B

  prep_kernel<<<dim3(256), dim3(256), 0, stream>>>(W_in, W_inner, Wt_in, Wt_inner, done);

  void* args[9];
  args[0] = (void*)&structure;
  args[1] = (void*)&features;
  args[2] = (void*)&b_in;
  args[3] = (void*)&b_inner;
  args[4] = (void*)&Wt_in;
  args[5] = (void*)&Wt_inner;
  args[6] = (void*)&state;
  args[7] = (void*)&done;
  args[8] = (void*)&out;
  hipLaunchCooperativeKernel((void*)tree_kernel, dim3(GRID), dim3(BLOCK), args, 0, stream);
}

// Round 5
// 452.079 us; speedup vs baseline: 2.1367x; 1.0043x over previous
//
#include <hip/hip_runtime.h>

#define NNODES 2000
#define BATCH  64
#define DIM    256
#define BLOCK  128
#define MAXGRID 1024

typedef __attribute__((ext_vector_type(8))) short  v8s;
typedef __attribute__((ext_vector_type(8))) __bf16 v8bf;
typedef __attribute__((ext_vector_type(4))) float  v4f;
typedef __attribute__((ext_vector_type(4))) int    v4i;

__device__ __forceinline__ short f2bf(float f) {
  unsigned u = __builtin_bit_cast(unsigned, f);
  u += 0x7FFFu + ((u >> 16) & 1u);            // RNE
  return (short)(u >> 16);
}
__device__ __forceinline__ float bf2f(short s) {
  unsigned u = ((unsigned)(unsigned short)s) << 16;
  return __builtin_bit_cast(float, u);
}
__device__ __forceinline__ v4f mfma16(v8s a, v8s b, v4f c) {
  return __builtin_amdgcn_mfma_f32_16x16x32_bf16(
      __builtin_bit_cast(v8bf, a), __builtin_bit_cast(v8bf, b), c, 0, 0, 0);
}
__device__ __forceinline__ float sigmoidf(float x) {
  return __builtin_amdgcn_rcpf(1.0f + __builtin_amdgcn_exp2f(-1.4426950408889634f * x));
}

// Prep: Wt_in[j][k] = bf16(W_in[k][j]) (256x256);
//       Wt_inner[j][k] = bf16(k<256 ? W_inner[k][j]+W_inner[k+256][j] : W_inner[k+256][j]) (256x512);
//       done[] = 0 (agent-scope so tree_kernel's relaxed loads see it).
__global__ void prep_kernel(const float* __restrict__ W_in, const float* __restrict__ W_inner,
                            short* __restrict__ Wt_in, short* __restrict__ Wt_inner,
                            int* __restrict__ done) {
  int idx = blockIdx.x * blockDim.x + threadIdx.x;
  int stride = gridDim.x * blockDim.x;
  for (int i = idx; i < 256 * 256; i += stride) {
    int j = i >> 8, k = i & 255;
    Wt_in[j * 256 + k] = f2bf(W_in[k * 256 + j]);
  }
  for (int i = idx; i < 256 * 512; i += stride) {
    int j = i >> 9, k = i & 511;
    float v = W_inner[(k + 256) * 256 + j];
    if (k < 256) v += W_inner[k * 256 + j];
    Wt_inner[j * 512 + k] = f2bf(v);
  }
  for (int i = idx; i < 2 * NNODES; i += stride)
    __hip_atomic_store(&done[i], 0, __ATOMIC_RELAXED, __HIP_MEMORY_SCOPE_AGENT);
}

// Dataflow tree evaluation, zero cache-flush fences (R4-verified sc0sc1/IF scheme),
// now with one (node, half) work-item per 128-thread block:
//  - the two batch-halves are independent end-to-end chains; separate blocks let
//    one half's poll/IF-handoff latency overlap the other's compute on the same CU
//  - up to 4 blocks/CU (8 waves) instead of 1 block (4 waves): 4 pipelines per CU
//  - serial rounds per block: 16 half-rounds -> ~4
// Item order: item = 2*node+half; all deps of item i have index > i; blocks walk
// items descending with stride gridDim.x; all blocks co-resident (cooperative).
// Grid size is computed from hipOccupancyMaxActiveBlocksPerMultiprocessor so the
// cooperative capacity check can never be exceeded (R1 lesson).
__launch_bounds__(BLOCK, 2)
__global__ void tree_kernel(const int* __restrict__ structure, const float* __restrict__ features,
                            const float* __restrict__ b_in, const float* __restrict__ b_inner,
                            const short* __restrict__ Wt_in, const short* __restrict__ Wt_inner,
                            short* __restrict__ state, int* done, float* __restrict__ out) {
  // 32 batch rows x 512 k (bf16), XOR-swizzled chunks: phys chunk = (k>>3) ^ (row&7).
  __shared__ short Xs[32 * 512];   // 32 KiB

  const int tid  = threadIdx.x;
  const int wave = tid >> 6;       // 0..1
  const int lane = tid & 63;
  const int ln15 = lane & 15;
  const int quad = lane >> 4;
  const int rl3  = ln15 & 7;

  const int bl  = tid >> 3;        // 0..15: base batch row this thread pools
  const int d0  = (tid & 7) << 5;  // dim block [d0, d0+32)
  const int swb = bl & 7;          // (bl+16)&7 == bl&7: swizzle base is rr-invariant

  // j = wave*128 + nt*16 + ln15 is node-invariant: hoist bias loads
  float bia_in[8], bia_nn[8];
  #pragma unroll
  for (int nt = 0; nt < 8; ++nt) {
    const int j = wave * 128 + nt * 16 + ln15;
    bia_in[nt] = b_in[j];
    bia_nn[nt] = b_inner[j];
  }

  for (int item = 2 * NNODES - 1 - (int)blockIdx.x; item >= 0; item -= (int)gridDim.x) {
    const int node = item >> 1;
    const int half = item & 1;
    const int s = structure[2 * node];
    const int e = structure[2 * node + 1];
    const bool leaf = (s < 0);
    const int nc = e - s;               // 1..4 when inner
    const int K = leaf ? 256 : 512;
    const short* __restrict__ W = leaf ? Wt_in : Wt_inner;

    // prefetch row rr=0's features BEFORE the poll: hides HBM/L2 latency under the wait
    const float* __restrict__ fp0 = features + ((size_t)(half * 32 + bl) * NNODES + node) * DIM + d0;
    float4 pre[8];
    #pragma unroll
    for (int q = 0; q < 8; ++q) pre[q] = ((const float4*)fp0)[q];

    if (!leaf && wave == 0 && lane < nc) {
      // relaxed agent-scope poll (reads IF, no cache invalidation)
      int g = 0;
      while (__hip_atomic_load(&done[2 * (s + lane) + half],
                               __ATOMIC_RELAXED, __HIP_MEMORY_SCOPE_AGENT) == 0 &&
             g < (1 << 22)) {
        __builtin_amdgcn_s_sleep(1); ++g;
      }
    }
    __syncthreads();   // children's half ready; also WAR on Xs from prior item

    // ---- build Xs (bf16): rows bl and bl+16 of this half's 32-row slab ----
    #pragma unroll
    for (int rr = 0; rr < 2; ++rr) {
      const int row = rr * 16 + bl;          // 0..31 within slab
      const int b   = half * 32 + row;
      const float* __restrict__ fp = features + ((size_t)b * NNODES + node) * DIM + d0;
      if (leaf) {
        #pragma unroll
        for (int dq = 0; dq < 4; ++dq) {
          const float4 f0 = rr ? ((const float4*)fp)[2 * dq]     : pre[2 * dq];
          const float4 f1 = rr ? ((const float4*)fp)[2 * dq + 1] : pre[2 * dq + 1];
          v8s o;
          o[0] = f2bf(f0.x); o[1] = f2bf(f0.y); o[2] = f2bf(f0.z); o[3] = f2bf(f0.w);
          o[4] = f2bf(f1.x); o[5] = f2bf(f1.y); o[6] = f2bf(f1.z); o[7] = f2bf(f1.w);
          const int ch = (d0 + dq * 8) >> 3;
          *(v8s*)&Xs[(row << 9) + ((ch ^ swb) << 3)] = o;
        }
      } else {
        // issue ALL child loads (sc0 sc1: bypass stale L1/L2, coherent at IF),
        // then one waitcnt -- IF latency paid once per row.
        v4i cb[4][4];
        #pragma unroll
        for (int ci = 0; ci < 4; ++ci) {
          if (ci < nc) {   // block-uniform branch
            const short* cp = state + ((size_t)(s + ci) * BATCH + b) * DIM + d0;
            #pragma unroll
            for (int dq = 0; dq < 4; ++dq)
              asm volatile("global_load_dwordx4 %0, %1, off sc0 sc1"
                           : "=v"(cb[ci][dq]) : "v"(cp + dq * 8));
          }
        }
        asm volatile("s_waitcnt vmcnt(0)" ::: "memory");
        __builtin_amdgcn_sched_barrier(0);   // rule #18: pin VALU uses after the wait

        const float inv = 1.0f / (float)(nc + 1);
        #pragma unroll
        for (int dq = 0; dq < 4; ++dq) {
          const float4 f0 = rr ? ((const float4*)fp)[2 * dq]     : pre[2 * dq];
          const float4 f1 = rr ? ((const float4*)fp)[2 * dq + 1] : pre[2 * dq + 1];
          float sm[8] = {f0.x, f0.y, f0.z, f0.w, f1.x, f1.y, f1.z, f1.w};
          float mn[8];
          #pragma unroll
          for (int q = 0; q < 8; ++q) mn[q] = sm[q];
          #pragma unroll
          for (int ci = 0; ci < 4; ++ci) {
            if (ci < nc) {
              const v8s cv = __builtin_bit_cast(v8s, cb[ci][dq]);
              #pragma unroll
              for (int q = 0; q < 8; ++q) {
                const float v = bf2f(cv[q]);
                sm[q] += v; mn[q] = fminf(mn[q], v);
              }
            }
          }
          v8s om, on;
          #pragma unroll
          for (int q = 0; q < 8; ++q) { om[q] = f2bf(sm[q] * inv); on[q] = f2bf(mn[q]); }
          const int ch = (d0 + dq * 8) >> 3;
          *(v8s*)&Xs[(row << 9) + ((ch ^ swb) << 3)]        = om;  // c_mean: k in [0,256)
          *(v8s*)&Xs[(row << 9) + (((ch + 32) ^ swb) << 3)] = on;  // c_min:  k in [256,512)
        }
      }
    }
    __syncthreads();   // Xs ready

    // ---- GEMM: [32 x K] @ Wt^T -> [32 x 256]; 2 waves x 128 cols each ----
    v4f acc[2][8];
    #pragma unroll
    for (int mt = 0; mt < 2; ++mt)
      #pragma unroll
      for (int nt = 0; nt < 8; ++nt) acc[mt][nt] = v4f{0.f, 0.f, 0.f, 0.f};

    const short* __restrict__ Wp = W + (size_t)(wave * 128 + ln15) * K + quad * 8;
    const int nkc = K >> 5;
    v8s bcur[8];
    #pragma unroll
    for (int nt = 0; nt < 8; ++nt) bcur[nt] = *(const v8s*)(Wp + (size_t)nt * 16 * K);
    for (int kc = 0; kc < nkc; ++kc) {
      const int kn = (kc + 1 < nkc) ? kc + 1 : kc;   // last iter: harmless re-load
      v8s bnxt[8];
      #pragma unroll
      for (int nt = 0; nt < 8; ++nt) bnxt[nt] = *(const v8s*)(Wp + (size_t)nt * 16 * K + kn * 32);
      v8s af[2];
      #pragma unroll
      for (int mt = 0; mt < 2; ++mt) {
        const int r = mt * 16 + ln15;               // r&7 == rl3
        af[mt] = *(const v8s*)&Xs[(r << 9) + (((kc * 4 + quad) ^ rl3) << 3)];
      }
      #pragma unroll
      for (int mt = 0; mt < 2; ++mt)
        #pragma unroll
        for (int nt = 0; nt < 8; ++nt)
          acc[mt][nt] = mfma16(af[mt], bcur[nt], acc[mt][nt]);
      #pragma unroll
      for (int nt = 0; nt < 8; ++nt) bcur[nt] = bnxt[nt];
    }

    // ---- epilogue: bias + sigmoid; state stored via sc0sc1 (coherent at IF) ----
    #pragma unroll
    for (int mt = 0; mt < 2; ++mt) {
      #pragma unroll
      for (int nt = 0; nt < 8; ++nt) {
        const int j = wave * 128 + nt * 16 + ln15;
        const float bs = leaf ? bia_in[nt] : bia_nn[nt];
        #pragma unroll
        for (int r = 0; r < 4; ++r) {
          const int bb = half * 32 + mt * 16 + quad * 4 + r;
          const float v = sigmoidf(acc[mt][nt][r] + bs);
          short* sp = state + ((size_t)node * BATCH + bb) * DIM + j;
          const int hv = (int)(unsigned short)f2bf(v);
          asm volatile("global_store_short %0, %1, off sc0 sc1" :: "v"(sp), "v"(hv));
          if (node == 0) out[bb * DIM + j] = v;
        }
      }
    }

    asm volatile("s_waitcnt vmcnt(0)" ::: "memory");  // this thread's stores are at IF
    __syncthreads();                                  // => ALL threads' stores are at IF
    if (tid == 0)
      __hip_atomic_store(&done[2 * node + half], 1,
                         __ATOMIC_RELAXED, __HIP_MEMORY_SCOPE_AGENT);
  }
}

extern "C" void kernel_launch(void* const* d_in, const int* in_sizes, int n_in,
                              void* d_out, int out_size, void* d_ws, size_t ws_size,
                              hipStream_t stream) {
  const int*   structure = (const int*)d_in[0];
  const float* features  = (const float*)d_in[1];
  const float* W_in      = (const float*)d_in[2];
  const float* b_in      = (const float*)d_in[3];
  const float* W_inner   = (const float*)d_in[4];
  const float* b_inner   = (const float*)d_in[5];
  float* out = (float*)d_out;

  char* ws = (char*)d_ws;
  short* state = (short*)ws;                                   // 2000*64*256*2 = 65,536,000 B
  size_t off = (size_t)NNODES * BATCH * DIM * 2;
  short* Wt_in = (short*)(ws + off);    off += 256 * 256 * 2;  // 131,072 B
  short* Wt_inner = (short*)(ws + off); off += 512 * 256 * 2;  // 262,144 B
  int* done = (int*)(ws + off);                                 // 2*2000*4 = 16,000 B

  prep_kernel<<<dim3(256), dim3(256), 0, stream>>>(W_in, W_inner, Wt_in, Wt_inner, done);

  // Cooperative capacity: never launch more blocks than are co-resident (R1 lesson).
  static int coop_grid = 0;
  if (coop_grid == 0) {
    int nb = 0;
    hipError_t err = hipOccupancyMaxActiveBlocksPerMultiprocessor(
        &nb, reinterpret_cast<const void*>(tree_kernel), BLOCK, 0);
    if (err != hipSuccess || nb < 1) nb = 1;
    long g = (long)nb * 256;
    if (g > MAXGRID) g = MAXGRID;
    coop_grid = (int)g;
  }

  void* args[9];
  args[0] = (void*)&structure;
  args[1] = (void*)&features;
  args[2] = (void*)&b_in;
  args[3] = (void*)&b_inner;
  args[4] = (void*)&Wt_in;
  args[5] = (void*)&Wt_inner;
  args[6] = (void*)&state;
  args[7] = (void*)&done;
  args[8] = (void*)&out;
  hipLaunchCooperativeKernel((void*)tree_kernel, dim3(coop_grid), dim3(BLOCK), args, 0, stream);
}